// Round 7
// baseline (1638.126 us; speedup 1.0000x reference)
//
#include <hip/hip_runtime.h>
#include <math.h>

#define BB    8
#define CC    64
#define NN    256
#define MM    20      // retained modes per axis
#define NKK   40      // retained row-modes: {0..19} U {236..255}
#define NLAY  3
#define FCD   128
#define PLANE (NN*NN)

// Fast tanh: clamp + exp-based. v_exp_f32/v_rcp_f32, ~1e-7 abs error, no branches.
__device__ __forceinline__ float fast_tanh(float x) {
    float xc = fminf(fmaxf(x, -15.f), 15.f);
    float e = __expf(2.f * xc);
    return (e - 1.f) / (e + 1.f);
}

// ---------------------------------------------------------------------------
// Basis precompute (double precision on device; tiny).
__global__ __launch_bounds__(256) void k_basis(float* __restrict__ FlT, float* __restrict__ FkT,
                                               float* __restrict__ BkT, float* __restrict__ BlT,
                                               float* __restrict__ CwT, const float* __restrict__ conv_w) {
    int t = threadIdx.x;
    const double PI = 3.14159265358979323846;
    for (int j = t; j < NN*MM; j += 256) {
        int y = j / MM, l = j % MM;
        double g = (y == 0 || y == NN-1) ? 1.0 : 2.0;
        FlT[j] = (float)(g * cos(PI * (double)(l*y) / (double)(NN-1)));
    }
    for (int j = t; j < NN*NKK; j += 256) {
        int x = j / NKK, k = j % NKK;
        int rk = (k < MM) ? k : (NN - NKK + k);
        double g = (x == 0 || x == NN-1) ? 1.0 : 2.0;
        FkT[j] = (float)(g * cos(PI * (double)(rk*x) / (double)(NN-1)));
    }
    for (int j = t; j < NKK*NN; j += 256) {
        int k = j / NN, p = j % NN;
        int rk = (k < MM) ? k : (NN - NKK + k);
        double g = (rk == 0 || rk == NN-1) ? 1.0 : 2.0;
        BkT[j] = (float)(g * cos(PI * (double)(rk*p) / (double)(NN-1)));
    }
    for (int j = t; j < MM*NN; j += 256) {
        int l = j / NN, q = j % NN;
        double g = (l == 0) ? 1.0 : 2.0;
        BlT[j] = (float)(g * cos(PI * (double)(q*l) / (double)(NN-1)));
    }
    for (int j = t; j < NLAY*CC*CC; j += 256) {
        int lay = j / (CC*CC), r = j % (CC*CC);
        int i = r / CC, o = r % CC;
        CwT[j] = conv_w[lay*CC*CC + o*CC + i];
    }
}

// ---------------------------------------------------------------------------
// fc0: h[b,c,p,q] = sum_d x[b,p,q,d]*w[d,c] + bias[c].  Block=(b,p), thread=q.
__global__ __launch_bounds__(256) void k_fc0(const float* __restrict__ xin, const float* __restrict__ w,
                                             const float* __restrict__ bias, float* __restrict__ h) {
    __shared__ float xs[NN*3];
    int b = blockIdx.x >> 8, p = blockIdx.x & 255, q = threadIdx.x;
    size_t rowbase = ((size_t)(b*NN + p)*NN) * 3;
    for (int j = q; j < NN*3; j += 256) xs[j] = xin[rowbase + j];
    __syncthreads();
    float v0 = xs[q*3+0], v1 = xs[q*3+1], v2 = xs[q*3+2];
    size_t obase = (size_t)b*CC*PLANE + (size_t)p*NN + q;
    #pragma unroll 8
    for (int c = 0; c < CC; ++c) {
        float hv = bias[c] + v0*w[c] + v1*w[CC+c] + v2*w[2*CC+c];
        h[obase + (size_t)c*PLANE] = hv;
    }
}

// ---------------------------------------------------------------------------
// Forward truncated DCT: per (b,c) plane, G[k,l] = Fk @ h @ FlT.
__global__ __launch_bounds__(256, 2) void k_fwd(const float* __restrict__ h, const float* __restrict__ FkT,
                                                const float* __restrict__ FlT, float* __restrict__ Gt) {
    __shared__ float P[NKK][NN+1];
    int plane = blockIdx.x;                 // b*CC + c
    int t = threadIdx.x;
    const float* hp = h + (size_t)plane * PLANE;
    float acc[NKK];
    #pragma unroll
    for (int k = 0; k < NKK; ++k) acc[k] = 0.f;
    #pragma unroll 2
    for (int x = 0; x < NN; ++x) {
        float hv = hp[x*NN + t];
        const float* fr = &FkT[x*NKK];      // wave-uniform address -> s_load
        #pragma unroll
        for (int k = 0; k < NKK; ++k) acc[k] += fr[k] * hv;
    }
    #pragma unroll
    for (int k = 0; k < NKK; ++k) P[k][t] = acc[k];
    __syncthreads();
    int b = plane >> 6, c = plane & 63;
    for (int j = t; j < NKK*MM; j += 256) {
        int k = j / MM, l = j % MM;
        float a = 0.f;
        for (int y = 0; y < NN; ++y) a += P[k][y] * FlT[y*MM + l];
        Gt[((size_t)(k*BB + b)*CC + c)*MM + l] = a;
    }
}

// ---------------------------------------------------------------------------
// Spectral mode-mix: S[b,k,l,o] = sum_i G[b,i,kb,l] * w[i,o,kk,l].
// S layout [b][k][l][o] (o contiguous) for coalesced k_inv1 / wave-uniform U rows.
__global__ __launch_bounds__(256, 2) void k_spec(const float* __restrict__ Gt, const float* __restrict__ w1,
                                                 const float* __restrict__ w2, float* __restrict__ S) {
    extern __shared__ float gl[];           // BB*CC*MM = 10240 floats ([b][c][l] order)
    int kb = blockIdx.x;
    int t = threadIdx.x;
    const float* chunk = Gt + (size_t)kb * (BB*CC*MM);
    for (int j = t; j < BB*CC*MM; j += 256) gl[j] = chunk[j];
    __syncthreads();
    int o = t & 63, g = t >> 6;
    int b0 = 2*g, b1 = 2*g + 1;
    const float* wp; int kk;
    if (kb < MM) { wp = w1; kk = kb; } else { wp = w2; kk = kb - MM; }
    float a0[MM], a1[MM];
    #pragma unroll
    for (int l = 0; l < MM; ++l) { a0[l] = 0.f; a1[l] = 0.f; }
    for (int i = 0; i < CC; ++i) {
        const float4* wr4 = reinterpret_cast<const float4*>(wp + ((size_t)(i*CC + o)*MM + kk)*MM);
        const float4* g04 = reinterpret_cast<const float4*>(&gl[(b0*CC + i)*MM]);
        const float4* g14 = reinterpret_cast<const float4*>(&gl[(b1*CC + i)*MM]);
        #pragma unroll
        for (int l4 = 0; l4 < MM/4; ++l4) {
            float4 wv = wr4[l4];
            float4 gv0 = g04[l4];
            float4 gv1 = g14[l4];
            a0[4*l4+0] += wv.x*gv0.x; a0[4*l4+1] += wv.y*gv0.y;
            a0[4*l4+2] += wv.z*gv0.z; a0[4*l4+3] += wv.w*gv0.w;
            a1[4*l4+0] += wv.x*gv1.x; a1[4*l4+1] += wv.y*gv1.y;
            a1[4*l4+2] += wv.z*gv1.z; a1[4*l4+3] += wv.w*gv1.w;
        }
    }
    #pragma unroll
    for (int l = 0; l < MM; ++l) {
        S[((size_t)(b0*NKK + kb)*MM + l)*CC + o] = a0[l];   // coalesced in o
        S[((size_t)(b1*NKK + kb)*MM + l)*CC + o] = a1[l];
    }
}

// ---------------------------------------------------------------------------
// Inverse stage 1: U[b,p,l,o] = sum_k BkT[k,p] * S[b,k,l,o].
// Block=(b,p); wave w handles l = w + 4j (j=0..4); lane = o. No LDS.
__global__ __launch_bounds__(256, 2) void k_inv1(const float* __restrict__ S, const float* __restrict__ BkT,
                                                 float* __restrict__ U) {
    int b = blockIdx.x >> 8, p = blockIdx.x & 255;
    int o = threadIdx.x & 63, w = threadIdx.x >> 6;
    float acc[5];
    #pragma unroll
    for (int j = 0; j < 5; ++j) acc[j] = 0.f;
    for (int k = 0; k < NKK; ++k) {
        float bk = BkT[k*NN + p];                       // wave-uniform
        const float* sb = S + ((size_t)(b*NKK + k)*MM + w)*CC + o;
        #pragma unroll
        for (int j = 0; j < 5; ++j) acc[j] += bk * sb[(size_t)(4*j)*CC];
    }
    float* ub = U + ((size_t)(b*NN + p)*MM + w)*CC + o;
    #pragma unroll
    for (int j = 0; j < 5; ++j) ub[(size_t)(4*j)*CC] = acc[j];
}

// ---------------------------------------------------------------------------
// Combine IN PLACE, ONE row per block, NO LDS:
//   h[b,o,p,q] = tanh( conv(h)[o] + cb[o] + sum_l U[b,p,l,o]*BlT[l,q] )
// Weights/U rows wave-uniform -> scalar pipe. ONE acc[64] per thread —
// round-7 lesson: two 64-float register arrays get demoted to scratch
// (VGPR_Count=80 < live set), one promotes (r6: VGPR=92).
__global__ __launch_bounds__(256, 2) void k_combine(float* h, const float* __restrict__ U,
                                                    const float* __restrict__ BlT, const float* __restrict__ cwt,
                                                    const float* __restrict__ cb) {
    int b = blockIdx.x >> 8, p = blockIdx.x & 255;
    int q = threadIdx.x;
    float acc[CC];
    #pragma unroll
    for (int o = 0; o < CC; ++o) acc[o] = cb[o];
    float* hb = h + (size_t)b*CC*PLANE + (size_t)p*NN + q;
    #pragma unroll 4
    for (int i = 0; i < CC; ++i) {
        float hv = hb[(size_t)i*PLANE];
        const float* wr = &cwt[i*CC];                   // wave-uniform -> s_load
        #pragma unroll
        for (int o = 0; o < CC; ++o) acc[o] += wr[o]*hv;
    }
    const float* ub = U + ((size_t)(b*NN + p)*MM)*CC;
    #pragma unroll 2
    for (int l = 0; l < MM; ++l) {
        float blv = BlT[l*NN + q];
        const float* ur = ub + (size_t)l*CC;            // wave-uniform row
        #pragma unroll
        for (int o = 0; o < CC; ++o) acc[o] += ur[o]*blv;
    }
    #pragma unroll
    for (int o = 0; o < CC; ++o) hb[(size_t)o*PLANE] = fast_tanh(acc[o]);
}

// ---------------------------------------------------------------------------
// Last layer, fused-linear (round-4 algebra) + ROUND-6 regrid.
// Round-6 evidence: v1 (per-thread 4 f-chunks) re-streamed h 4x ->
// FETCH 252 MB vs 145 ideal, latency-bound at 243 µs (VALUBusy 55%,
// Occ 53%). Fix: split f ACROSS WAVES, not across time. Block =
// (b, p, q-chunk of 64); 256 thr = 4 waves x 64 lanes; wave w owns
// f in [32w, 32w+32), lane owns pixel q. h read ONCE per pixel (4
// waves read identical rows -> L1 broadcast); a[32] live set keeps
// VGPR ~48 (no demotion); 8192 blocks -> 4x TLP. Wave partials
// reduced via 1 KB LDS. Phase A (ul) recomputed per q-chunk (4x
// redundant, ~17 µs aggregate - cheap vs the re-fetch it removes).
__global__ __launch_bounds__(256) void k_fuse_w(const float* __restrict__ cwt, const float* __restrict__ cb,
        const float* __restrict__ w1, const float* __restrict__ b1,
        float* __restrict__ Wt, float* __restrict__ bt) {
    int idx = blockIdx.x*256 + threadIdx.x;     // [0, CC*FCD)
    int j = idx >> 7, f = idx & 127;
    float s = 0.f;
    #pragma unroll 8
    for (int i = 0; i < CC; ++i) s += cwt[j*CC + i] * w1[i*FCD + f];
    Wt[idx] = s;
    if (idx < FCD) {
        float sb = b1[idx];
        for (int i = 0; i < CC; ++i) sb += cb[i] * w1[i*FCD + idx];
        bt[idx] = sb;
    }
}

__global__ __launch_bounds__(256, 4) void k_fc_last(const float* __restrict__ h, const float* __restrict__ U,
        const float* __restrict__ BlT, const float* __restrict__ w1,
        const float* __restrict__ Wt, const float* __restrict__ bt,
        const float* __restrict__ w2, const float* __restrict__ b2, float* __restrict__ out) {
    __shared__ float ul[MM*FCD];                // 20x128 = 10 KB
    __shared__ float red[4][64];                // wave partials, 1 KB
    int qc = blockIdx.x & 3;
    int p  = (blockIdx.x >> 2) & 255;
    int b  = blockIdx.x >> 10;
    int lane = threadIdx.x & 63, w = threadIdx.x >> 6;
    int q  = qc*64 + lane;
    int f0 = w*32;
    // Phase A: ul[l][f] = sum_o U[b,p,l,o] * w1[o,f]  (cooperative, 640 FMA/thr)
    const float* ub = U + ((size_t)(b*NN + p)*MM)*CC;
    for (int idx = threadIdx.x; idx < MM*FCD; idx += 256) {
        int l = idx >> 7, f = idx & 127;
        const float* ur = ub + l*CC;            // row shared across f-threads -> broadcast
        float s = 0.f;
        #pragma unroll 8
        for (int o = 0; o < CC; ++o) s += ur[o] * w1[o*FCD + f];   // w1 coalesced in f
        ul[idx] = s;
    }
    __syncthreads();
    // Phase B: each thread = (pixel q, f-chunk w). h read ONCE per pixel.
    const float* hb = h + (size_t)b*CC*PLANE + (size_t)p*NN + q;
    float a[32];
    #pragma unroll
    for (int f = 0; f < 32; ++f) a[f] = bt[f0 + f];
    #pragma unroll 4
    for (int j = 0; j < CC; ++j) {
        float hv = hb[(size_t)j*PLANE];         // coalesced across lanes; waves share rows
        const float* wr = &Wt[j*FCD + f0];      // wave-uniform -> s_load
        #pragma unroll
        for (int f = 0; f < 32; ++f) a[f] += hv*wr[f];
    }
    #pragma unroll 2
    for (int l = 0; l < MM; ++l) {
        float blv = BlT[l*NN + q];
        const float* ur = &ul[l*FCD + f0];      // wave-uniform LDS row -> broadcast
        #pragma unroll
        for (int f = 0; f < 32; ++f) a[f] += blv*ur[f];
    }
    float pv = 0.f;
    #pragma unroll
    for (int f = 0; f < 32; ++f) pv += fast_tanh(a[f]) * w2[f0 + f];
    red[w][lane] = pv;
    __syncthreads();
    if (w == 0) {
        float ov = b2[0] + red[0][lane] + red[1][lane] + red[2][lane] + red[3][lane];
        out[((size_t)(b*NN + p))*NN + q] = ov;
    }
}

// ---------------------------------------------------------------------------
extern "C" void kernel_launch(void* const* d_in, const int* in_sizes, int n_in,
                              void* d_out, int out_size, void* d_ws, size_t ws_size,
                              hipStream_t stream) {
    const float* x      = (const float*)d_in[0];
    const float* fc0_w  = (const float*)d_in[1];
    const float* fc0_b  = (const float*)d_in[2];
    const float* sp_w1  = (const float*)d_in[3];
    const float* sp_w2  = (const float*)d_in[4];
    const float* conv_w = (const float*)d_in[5];
    const float* conv_b = (const float*)d_in[6];
    const float* fc1_w  = (const float*)d_in[7];
    const float* fc1_b  = (const float*)d_in[8];
    const float* fc2_w  = (const float*)d_in[9];
    const float* fc2_b  = (const float*)d_in[10];

    float* ws = (float*)d_ws;
    const size_t HSZ = (size_t)BB*CC*PLANE;           // 33,554,432 floats (134.2 MB)
    float* hA  = ws;
    float* Gt  = hA + HSZ;                            // NKK*BB*CC*MM = 409,600
    float* S   = Gt + (size_t)NKK*BB*CC*MM;           // BB*NKK*MM*CC = 409,600
    float* U   = S  + (size_t)BB*NKK*MM*CC;           // BB*NN*MM*CC  = 2,621,440
    float* FlT = U  + (size_t)BB*NN*MM*CC;            // NN*MM   =  5,120
    float* FkT = FlT + NN*MM;                         // NN*NKK  = 10,240
    float* BkT = FkT + NN*NKK;                        // NKK*NN  = 10,240
    float* BlT = BkT + NKK*NN;                        // MM*NN   =  5,120
    float* CwT = BlT + MM*NN;                         // NLAY*CC*CC = 12,288
    float* Wt  = CwT + NLAY*CC*CC;                    // CC*FCD  =  8,192
    float* bt  = Wt  + CC*FCD;                        // FCD     =    128
    // total = 37,046,400 floats = 148.2 MB of workspace

    k_basis<<<1, 256, 0, stream>>>(FlT, FkT, BkT, BlT, CwT, conv_w);
    k_fc0<<<BB*NN, 256, 0, stream>>>(x, fc0_w, fc0_b, hA);
    // Layer-constant fused fc weights for the last layer (off critical path).
    k_fuse_w<<<CC*FCD/256, 256, 0, stream>>>(CwT + (NLAY-1)*CC*CC, conv_b + (NLAY-1)*CC,
                                             fc1_w, fc1_b, Wt, bt);

    for (int lay = 0; lay < NLAY; ++lay) {
        const float* w1 = sp_w1 + (size_t)lay*CC*CC*MM*MM;
        const float* w2 = sp_w2 + (size_t)lay*CC*CC*MM*MM;
        k_fwd<<<BB*CC, 256, 0, stream>>>(hA, FkT, FlT, Gt);
        k_spec<<<NKK, 256, BB*CC*MM*sizeof(float), stream>>>(Gt, w1, w2, S);
        k_inv1<<<BB*NN, 256, 0, stream>>>(S, BkT, U);
        if (lay != NLAY-1) {
            k_combine<<<BB*NN, 256, 0, stream>>>(
                hA, U, BlT, CwT + lay*CC*CC, conv_b + lay*CC);
        } else {
            k_fc_last<<<BB*NN*4, 256, 0, stream>>>(
                hA, U, BlT, fc1_w, Wt, bt, fc2_w, fc2_b, (float*)d_out);
        }
    }
}

// Round 10
// 1123.167 us; speedup vs baseline: 1.4585x; 1.4585x over previous
//
#include <hip/hip_runtime.h>
#include <math.h>

#define BB    8
#define CC    64
#define NN    256
#define MM    20      // retained modes per axis
#define NKK   40      // retained row-modes: {0..19} U {236..255}
#define NLAY  3
#define FCD   128
#define PLANE (NN*NN)

// Fast tanh: clamp + exp-based. v_exp_f32/v_rcp_f32, ~1e-7 abs error, no branches.
__device__ __forceinline__ float fast_tanh(float x) {
    float xc = fminf(fmaxf(x, -15.f), 15.f);
    float e = __expf(2.f * xc);
    return (e - 1.f) / (e + 1.f);
}

// ---------------------------------------------------------------------------
// Basis precompute (double precision on device; tiny).
__global__ __launch_bounds__(256) void k_basis(float* __restrict__ FlT, float* __restrict__ FkT,
                                               float* __restrict__ BkT, float* __restrict__ BlT,
                                               float* __restrict__ CwT, const float* __restrict__ conv_w) {
    int t = threadIdx.x;
    const double PI = 3.14159265358979323846;
    for (int j = t; j < NN*MM; j += 256) {
        int y = j / MM, l = j % MM;
        double g = (y == 0 || y == NN-1) ? 1.0 : 2.0;
        FlT[j] = (float)(g * cos(PI * (double)(l*y) / (double)(NN-1)));
    }
    for (int j = t; j < NN*NKK; j += 256) {
        int x = j / NKK, k = j % NKK;
        int rk = (k < MM) ? k : (NN - NKK + k);
        double g = (x == 0 || x == NN-1) ? 1.0 : 2.0;
        FkT[j] = (float)(g * cos(PI * (double)(rk*x) / (double)(NN-1)));
    }
    for (int j = t; j < NKK*NN; j += 256) {
        int k = j / NN, p = j % NN;
        int rk = (k < MM) ? k : (NN - NKK + k);
        double g = (rk == 0 || rk == NN-1) ? 1.0 : 2.0;
        BkT[j] = (float)(g * cos(PI * (double)(rk*p) / (double)(NN-1)));
    }
    for (int j = t; j < MM*NN; j += 256) {
        int l = j / NN, q = j % NN;
        double g = (l == 0) ? 1.0 : 2.0;
        BlT[j] = (float)(g * cos(PI * (double)(q*l) / (double)(NN-1)));
    }
    for (int j = t; j < NLAY*CC*CC; j += 256) {
        int lay = j / (CC*CC), r = j % (CC*CC);
        int i = r / CC, o = r % CC;
        CwT[j] = conv_w[lay*CC*CC + o*CC + i];
    }
}

// ---------------------------------------------------------------------------
// fc0: h[b,c,p,q] = sum_d x[b,p,q,d]*w[d,c] + bias[c].  Block=(b,p), thread=q.
__global__ __launch_bounds__(256) void k_fc0(const float* __restrict__ xin, const float* __restrict__ w,
                                             const float* __restrict__ bias, float* __restrict__ h) {
    __shared__ float xs[NN*3];
    int b = blockIdx.x >> 8, p = blockIdx.x & 255, q = threadIdx.x;
    size_t rowbase = ((size_t)(b*NN + p)*NN) * 3;
    for (int j = q; j < NN*3; j += 256) xs[j] = xin[rowbase + j];
    __syncthreads();
    float v0 = xs[q*3+0], v1 = xs[q*3+1], v2 = xs[q*3+2];
    size_t obase = (size_t)b*CC*PLANE + (size_t)p*NN + q;
    #pragma unroll 8
    for (int c = 0; c < CC; ++c) {
        float hv = bias[c] + v0*w[c] + v1*w[CC+c] + v2*w[2*CC+c];
        h[obase + (size_t)c*PLANE] = hv;
    }
}

// ---------------------------------------------------------------------------
// Forward truncated DCT: per (b,c) plane, G[k,l] = Fk @ h @ FlT.
__global__ __launch_bounds__(256, 2) void k_fwd(const float* __restrict__ h, const float* __restrict__ FkT,
                                                const float* __restrict__ FlT, float* __restrict__ Gt) {
    __shared__ float P[NKK][NN+1];
    int plane = blockIdx.x;                 // b*CC + c
    int t = threadIdx.x;
    const float* hp = h + (size_t)plane * PLANE;
    float acc[NKK];
    #pragma unroll
    for (int k = 0; k < NKK; ++k) acc[k] = 0.f;
    #pragma unroll 2
    for (int x = 0; x < NN; ++x) {
        float hv = hp[x*NN + t];
        const float* fr = &FkT[x*NKK];      // wave-uniform address -> s_load
        #pragma unroll
        for (int k = 0; k < NKK; ++k) acc[k] += fr[k] * hv;
    }
    #pragma unroll
    for (int k = 0; k < NKK; ++k) P[k][t] = acc[k];
    __syncthreads();
    int b = plane >> 6, c = plane & 63;
    for (int j = t; j < NKK*MM; j += 256) {
        int k = j / MM, l = j % MM;
        float a = 0.f;
        for (int y = 0; y < NN; ++y) a += P[k][y] * FlT[y*MM + l];
        Gt[((size_t)(k*BB + b)*CC + c)*MM + l] = a;
    }
}

// ---------------------------------------------------------------------------
// Spectral mode-mix: S[b,k,l,o] = sum_i G[b,i,kb,l] * w[i,o,kk,l].
// S layout [b][k][l][o] (o contiguous) for coalesced k_inv1 / wave-uniform U rows.
__global__ __launch_bounds__(256, 2) void k_spec(const float* __restrict__ Gt, const float* __restrict__ w1,
                                                 const float* __restrict__ w2, float* __restrict__ S) {
    extern __shared__ float gl[];           // BB*CC*MM = 10240 floats ([b][c][l] order)
    int kb = blockIdx.x;
    int t = threadIdx.x;
    const float* chunk = Gt + (size_t)kb * (BB*CC*MM);
    for (int j = t; j < BB*CC*MM; j += 256) gl[j] = chunk[j];
    __syncthreads();
    int o = t & 63, g = t >> 6;
    int b0 = 2*g, b1 = 2*g + 1;
    const float* wp; int kk;
    if (kb < MM) { wp = w1; kk = kb; } else { wp = w2; kk = kb - MM; }
    float a0[MM], a1[MM];
    #pragma unroll
    for (int l = 0; l < MM; ++l) { a0[l] = 0.f; a1[l] = 0.f; }
    for (int i = 0; i < CC; ++i) {
        const float4* wr4 = reinterpret_cast<const float4*>(wp + ((size_t)(i*CC + o)*MM + kk)*MM);
        const float4* g04 = reinterpret_cast<const float4*>(&gl[(b0*CC + i)*MM]);
        const float4* g14 = reinterpret_cast<const float4*>(&gl[(b1*CC + i)*MM]);
        #pragma unroll
        for (int l4 = 0; l4 < MM/4; ++l4) {
            float4 wv = wr4[l4];
            float4 gv0 = g04[l4];
            float4 gv1 = g14[l4];
            a0[4*l4+0] += wv.x*gv0.x; a0[4*l4+1] += wv.y*gv0.y;
            a0[4*l4+2] += wv.z*gv0.z; a0[4*l4+3] += wv.w*gv0.w;
            a1[4*l4+0] += wv.x*gv1.x; a1[4*l4+1] += wv.y*gv1.y;
            a1[4*l4+2] += wv.z*gv1.z; a1[4*l4+3] += wv.w*gv1.w;
        }
    }
    #pragma unroll
    for (int l = 0; l < MM; ++l) {
        S[((size_t)(b0*NKK + kb)*MM + l)*CC + o] = a0[l];   // coalesced in o
        S[((size_t)(b1*NKK + kb)*MM + l)*CC + o] = a1[l];
    }
}

// ---------------------------------------------------------------------------
// Inverse stage 1: U[b,p,l,o] = sum_k BkT[k,p] * S[b,k,l,o].
// Block=(b,p); wave w handles l = w + 4j (j=0..4); lane = o. No LDS.
__global__ __launch_bounds__(256, 2) void k_inv1(const float* __restrict__ S, const float* __restrict__ BkT,
                                                 float* __restrict__ U) {
    int b = blockIdx.x >> 8, p = blockIdx.x & 255;
    int o = threadIdx.x & 63, w = threadIdx.x >> 6;
    float acc[5];
    #pragma unroll
    for (int j = 0; j < 5; ++j) acc[j] = 0.f;
    for (int k = 0; k < NKK; ++k) {
        float bk = BkT[k*NN + p];                       // wave-uniform
        const float* sb = S + ((size_t)(b*NKK + k)*MM + w)*CC + o;
        #pragma unroll
        for (int j = 0; j < 5; ++j) acc[j] += bk * sb[(size_t)(4*j)*CC];
    }
    float* ub = U + ((size_t)(b*NN + p)*MM + w)*CC + o;
    #pragma unroll
    for (int j = 0; j < 5; ++j) ub[(size_t)(4*j)*CC] = acc[j];
}

// ---------------------------------------------------------------------------
// Combine IN PLACE, ONE row per block, NO LDS:
//   h[b,o,p,q] = tanh( conv(h)[o] + cb[o] + sum_l U[b,p,l,o]*BlT[l,q] )
// Weights/U rows wave-uniform -> scalar pipe. ONE acc[64] per thread —
// round-7 lesson: two 64-float register arrays get demoted to scratch
// (VGPR_Count=80 < live set), one promotes (r6: VGPR=92).
__global__ __launch_bounds__(256, 2) void k_combine(float* h, const float* __restrict__ U,
                                                    const float* __restrict__ BlT, const float* __restrict__ cwt,
                                                    const float* __restrict__ cb) {
    int b = blockIdx.x >> 8, p = blockIdx.x & 255;
    int q = threadIdx.x;
    float acc[CC];
    #pragma unroll
    for (int o = 0; o < CC; ++o) acc[o] = cb[o];
    float* hb = h + (size_t)b*CC*PLANE + (size_t)p*NN + q;
    #pragma unroll 4
    for (int i = 0; i < CC; ++i) {
        float hv = hb[(size_t)i*PLANE];
        const float* wr = &cwt[i*CC];                   // wave-uniform -> s_load
        #pragma unroll
        for (int o = 0; o < CC; ++o) acc[o] += wr[o]*hv;
    }
    const float* ub = U + ((size_t)(b*NN + p)*MM)*CC;
    #pragma unroll 2
    for (int l = 0; l < MM; ++l) {
        float blv = BlT[l*NN + q];
        const float* ur = ub + (size_t)l*CC;            // wave-uniform row
        #pragma unroll
        for (int o = 0; o < CC; ++o) acc[o] += ur[o]*blv;
    }
    #pragma unroll
    for (int o = 0; o < CC; ++o) hb[(size_t)o*PLANE] = fast_tanh(acc[o]);
}

// ---------------------------------------------------------------------------
// Last layer, fused-linear (round-4 algebra) + round-6 regrid + ROUND-7 FIX.
// Round-7 evidence: splitting f across waves (f0 = (tid>>6)*32) broke the
// compiler's wave-uniformity proof -> SGPR_Count collapsed 112->32, all
// Wt/ul row reads became per-lane vector loads of identical addresses,
// VALUBusy 55->20%, dur 243->846 µs (FETCH=86 MB confirmed cache-hot —
// pure issue/latency poison, not bandwidth). FIX: readfirstlane the wave
// index (and Phase A's row index) — semantically a no-op (value IS
// wave-uniform) but moves it to an SGPR, restoring s_load weight
// addressing and LDS broadcast reads. h still read exactly once.
__global__ __launch_bounds__(256) void k_fuse_w(const float* __restrict__ cwt, const float* __restrict__ cb,
        const float* __restrict__ w1, const float* __restrict__ b1,
        float* __restrict__ Wt, float* __restrict__ bt) {
    int idx = blockIdx.x*256 + threadIdx.x;     // [0, CC*FCD)
    int j = idx >> 7, f = idx & 127;
    float s = 0.f;
    #pragma unroll 8
    for (int i = 0; i < CC; ++i) s += cwt[j*CC + i] * w1[i*FCD + f];
    Wt[idx] = s;
    if (idx < FCD) {
        float sb = b1[idx];
        for (int i = 0; i < CC; ++i) sb += cb[i] * w1[i*FCD + idx];
        bt[idx] = sb;
    }
}

__global__ __launch_bounds__(256, 4) void k_fc_last(const float* __restrict__ h, const float* __restrict__ U,
        const float* __restrict__ BlT, const float* __restrict__ w1,
        const float* __restrict__ Wt, const float* __restrict__ bt,
        const float* __restrict__ w2, const float* __restrict__ b2, float* __restrict__ out) {
    __shared__ float ul[MM*FCD];                // 20x128 = 10 KB
    __shared__ float red[4][64];                // wave partials, 1 KB
    int qc = blockIdx.x & 3;
    int p  = (blockIdx.x >> 2) & 255;
    int b  = blockIdx.x >> 10;
    int lane = threadIdx.x & 63;
    // readfirstlane: provably wave-uniform; forces SGPR residency so the
    // compiler emits s_load for weight rows (round-7 lesson: without this,
    // SGPR=32 and every weight read is a per-lane vector load).
    int w  = __builtin_amdgcn_readfirstlane(threadIdx.x >> 6);
    int q  = qc*64 + lane;
    int f0 = w*32;
    // Phase A: ul[l][f] = sum_o U[b,p,l,o] * w1[o,f]  (cooperative, 640 FMA/thr)
    const float* ub = U + ((size_t)(b*NN + p)*MM)*CC;
    for (int it = 0; it < MM*FCD/256; ++it) {
        int idx = it*256 + threadIdx.x;
        int l = __builtin_amdgcn_readfirstlane(idx >> 7);   // wave-uniform row
        int f = idx & 127;
        const float* ur = ub + l*CC;            // uniform row -> s_load
        float s = 0.f;
        #pragma unroll 8
        for (int o = 0; o < CC; ++o) s += ur[o] * w1[o*FCD + f];   // w1 coalesced in f
        ul[idx] = s;
    }
    __syncthreads();
    // Phase B: each thread = (pixel q, f-chunk w). h read ONCE per pixel.
    const float* hb = h + (size_t)b*CC*PLANE + (size_t)p*NN + q;
    float a[32];
    #pragma unroll
    for (int f = 0; f < 32; ++f) a[f] = bt[f0 + f];
    #pragma unroll 4
    for (int j = 0; j < CC; ++j) {
        float hv = hb[(size_t)j*PLANE];         // coalesced across lanes; waves share rows
        const float* wr = &Wt[j*FCD + f0];      // uniform -> s_load
        #pragma unroll
        for (int f = 0; f < 32; ++f) a[f] += hv*wr[f];
    }
    #pragma unroll 2
    for (int l = 0; l < MM; ++l) {
        float blv = BlT[l*NN + q];
        const float* ur = &ul[l*FCD + f0];      // uniform LDS row -> broadcast
        #pragma unroll
        for (int f = 0; f < 32; ++f) a[f] += blv*ur[f];
    }
    float pv = 0.f;
    #pragma unroll
    for (int f = 0; f < 32; ++f) pv += fast_tanh(a[f]) * w2[f0 + f];
    red[w][lane] = pv;
    __syncthreads();
    if (w == 0) {
        float ov = b2[0] + red[0][lane] + red[1][lane] + red[2][lane] + red[3][lane];
        out[((size_t)(b*NN + p))*NN + q] = ov;
    }
}

// ---------------------------------------------------------------------------
extern "C" void kernel_launch(void* const* d_in, const int* in_sizes, int n_in,
                              void* d_out, int out_size, void* d_ws, size_t ws_size,
                              hipStream_t stream) {
    const float* x      = (const float*)d_in[0];
    const float* fc0_w  = (const float*)d_in[1];
    const float* fc0_b  = (const float*)d_in[2];
    const float* sp_w1  = (const float*)d_in[3];
    const float* sp_w2  = (const float*)d_in[4];
    const float* conv_w = (const float*)d_in[5];
    const float* conv_b = (const float*)d_in[6];
    const float* fc1_w  = (const float*)d_in[7];
    const float* fc1_b  = (const float*)d_in[8];
    const float* fc2_w  = (const float*)d_in[9];
    const float* fc2_b  = (const float*)d_in[10];

    float* ws = (float*)d_ws;
    const size_t HSZ = (size_t)BB*CC*PLANE;           // 33,554,432 floats (134.2 MB)
    float* hA  = ws;
    float* Gt  = hA + HSZ;                            // NKK*BB*CC*MM = 409,600
    float* S   = Gt + (size_t)NKK*BB*CC*MM;           // BB*NKK*MM*CC = 409,600
    float* U   = S  + (size_t)BB*NKK*MM*CC;           // BB*NN*MM*CC  = 2,621,440
    float* FlT = U  + (size_t)BB*NN*MM*CC;            // NN*MM   =  5,120
    float* FkT = FlT + NN*MM;                         // NN*NKK  = 10,240
    float* BkT = FkT + NN*NKK;                        // NKK*NN  = 10,240
    float* BlT = BkT + NKK*NN;                        // MM*NN   =  5,120
    float* CwT = BlT + MM*NN;                         // NLAY*CC*CC = 12,288
    float* Wt  = CwT + NLAY*CC*CC;                    // CC*FCD  =  8,192
    float* bt  = Wt  + CC*FCD;                        // FCD     =    128
    // total = 37,046,400 floats = 148.2 MB of workspace

    k_basis<<<1, 256, 0, stream>>>(FlT, FkT, BkT, BlT, CwT, conv_w);
    k_fc0<<<BB*NN, 256, 0, stream>>>(x, fc0_w, fc0_b, hA);
    // Layer-constant fused fc weights for the last layer (off critical path).
    k_fuse_w<<<CC*FCD/256, 256, 0, stream>>>(CwT + (NLAY-1)*CC*CC, conv_b + (NLAY-1)*CC,
                                             fc1_w, fc1_b, Wt, bt);

    for (int lay = 0; lay < NLAY; ++lay) {
        const float* w1 = sp_w1 + (size_t)lay*CC*CC*MM*MM;
        const float* w2 = sp_w2 + (size_t)lay*CC*CC*MM*MM;
        k_fwd<<<BB*CC, 256, 0, stream>>>(hA, FkT, FlT, Gt);
        k_spec<<<NKK, 256, BB*CC*MM*sizeof(float), stream>>>(Gt, w1, w2, S);
        k_inv1<<<BB*NN, 256, 0, stream>>>(S, BkT, U);
        if (lay != NLAY-1) {
            k_combine<<<BB*NN, 256, 0, stream>>>(
                hA, U, BlT, CwT + lay*CC*CC, conv_b + lay*CC);
        } else {
            k_fc_last<<<BB*NN*4, 256, 0, stream>>>(
                hA, U, BlT, fc1_w, Wt, bt, fc2_w, fc2_b, (float*)d_out);
        }
    }
}

// Round 11
// 1072.982 us; speedup vs baseline: 1.5267x; 1.0468x over previous
//
#include <hip/hip_runtime.h>
#include <math.h>

#define BB    8
#define CC    64
#define NN    256
#define MM    20      // retained modes per axis
#define NKK   40      // retained row-modes: {0..19} U {236..255}
#define NLAY  3
#define FCD   128
#define PLANE (NN*NN)

// Fast tanh: clamp + exp-based. v_exp_f32/v_rcp_f32, ~1e-7 abs error, no branches.
__device__ __forceinline__ float fast_tanh(float x) {
    float xc = fminf(fmaxf(x, -15.f), 15.f);
    float e = __expf(2.f * xc);
    return (e - 1.f) / (e + 1.f);
}

// ---------------------------------------------------------------------------
// Basis precompute (double precision on device; tiny).
__global__ __launch_bounds__(256) void k_basis(float* __restrict__ FlT, float* __restrict__ FkT,
                                               float* __restrict__ BkT, float* __restrict__ BlT,
                                               float* __restrict__ CwT, const float* __restrict__ conv_w) {
    int t = threadIdx.x;
    const double PI = 3.14159265358979323846;
    for (int j = t; j < NN*MM; j += 256) {
        int y = j / MM, l = j % MM;
        double g = (y == 0 || y == NN-1) ? 1.0 : 2.0;
        FlT[j] = (float)(g * cos(PI * (double)(l*y) / (double)(NN-1)));
    }
    for (int j = t; j < NN*NKK; j += 256) {
        int x = j / NKK, k = j % NKK;
        int rk = (k < MM) ? k : (NN - NKK + k);
        double g = (x == 0 || x == NN-1) ? 1.0 : 2.0;
        FkT[j] = (float)(g * cos(PI * (double)(rk*x) / (double)(NN-1)));
    }
    for (int j = t; j < NKK*NN; j += 256) {
        int k = j / NN, p = j % NN;
        int rk = (k < MM) ? k : (NN - NKK + k);
        double g = (rk == 0 || rk == NN-1) ? 1.0 : 2.0;
        BkT[j] = (float)(g * cos(PI * (double)(rk*p) / (double)(NN-1)));
    }
    for (int j = t; j < MM*NN; j += 256) {
        int l = j / NN, q = j % NN;
        double g = (l == 0) ? 1.0 : 2.0;
        BlT[j] = (float)(g * cos(PI * (double)(q*l) / (double)(NN-1)));
    }
    for (int j = t; j < NLAY*CC*CC; j += 256) {
        int lay = j / (CC*CC), r = j % (CC*CC);
        int i = r / CC, o = r % CC;
        CwT[j] = conv_w[lay*CC*CC + o*CC + i];
    }
}

// ---------------------------------------------------------------------------
// fc0: h[b,c,p,q] = sum_d x[b,p,q,d]*w[d,c] + bias[c].  Block=(b,p), thread=q.
__global__ __launch_bounds__(256) void k_fc0(const float* __restrict__ xin, const float* __restrict__ w,
                                             const float* __restrict__ bias, float* __restrict__ h) {
    __shared__ float xs[NN*3];
    int b = blockIdx.x >> 8, p = blockIdx.x & 255, q = threadIdx.x;
    size_t rowbase = ((size_t)(b*NN + p)*NN) * 3;
    for (int j = q; j < NN*3; j += 256) xs[j] = xin[rowbase + j];
    __syncthreads();
    float v0 = xs[q*3+0], v1 = xs[q*3+1], v2 = xs[q*3+2];
    size_t obase = (size_t)b*CC*PLANE + (size_t)p*NN + q;
    #pragma unroll 8
    for (int c = 0; c < CC; ++c) {
        float hv = bias[c] + v0*w[c] + v1*w[CC+c] + v2*w[2*CC+c];
        h[obase + (size_t)c*PLANE] = hv;
    }
}

// ---------------------------------------------------------------------------
// Forward truncated DCT, ROUND-10 K-SPLIT: block = (plane, kgroup of 20 rows).
// Old shape: 512 blocks = 2 blocks/CU = 2 waves/SIMD — a serial x-loop of
// {1 global load -> 40 dependent FMA} cannot hide 200-900cy load latency at
// that residency (same latency disease as k_fc_last r6/r10). Split the 40
// retained k-modes into 2 groups of 20: acc[40]->acc[20] (lower VGPR), grid
// 512->1024 (4 blocks/CU), LDS 41->20.6 KB. h read 2x per k_fwd (+134 MB ->
// +21 µs HBM — cheap vs the latency it buys). Accumulation order per output
// bit-identical. Split-4 rejected: 536 MB fetch would flip HBM-bound.
__global__ __launch_bounds__(256, 4) void k_fwd(const float* __restrict__ h, const float* __restrict__ FkT,
                                                const float* __restrict__ FlT, float* __restrict__ Gt) {
    __shared__ float P[MM][NN+1];           // 20 x 257 floats = 20.6 KB
    int plane = blockIdx.x >> 1;            // b*CC + c
    int g = blockIdx.x & 1;                 // k-group: rows [20g, 20g+20)
    int t = threadIdx.x;
    const float* hp = h + (size_t)plane * PLANE;
    const float* fk = FkT + g*MM;           // this group's 20 columns of FkT rows
    float acc[MM];
    #pragma unroll
    for (int k = 0; k < MM; ++k) acc[k] = 0.f;
    #pragma unroll 4
    for (int x = 0; x < NN; ++x) {
        float hv = hp[x*NN + t];
        const float* fr = &fk[x*NKK];       // wave-uniform address -> s_load
        #pragma unroll
        for (int k = 0; k < MM; ++k) acc[k] += fr[k] * hv;
    }
    #pragma unroll
    for (int k = 0; k < MM; ++k) P[k][t] = acc[k];
    __syncthreads();
    int b = plane >> 6, c = plane & 63;
    for (int j = t; j < MM*MM; j += 256) {  // 400 outputs, 2 iters
        int kk = j / MM, l = j % MM;
        float a = 0.f;
        for (int y = 0; y < NN; ++y) a += P[kk][y] * FlT[y*MM + l];
        Gt[((size_t)((g*MM + kk)*BB + b)*CC + c)*MM + l] = a;
    }
}

// ---------------------------------------------------------------------------
// Spectral mode-mix: S[b,k,l,o] = sum_i G[b,i,kb,l] * w[i,o,kk,l].
// S layout [b][k][l][o] (o contiguous) for coalesced k_inv1 / wave-uniform U rows.
__global__ __launch_bounds__(256, 2) void k_spec(const float* __restrict__ Gt, const float* __restrict__ w1,
                                                 const float* __restrict__ w2, float* __restrict__ S) {
    extern __shared__ float gl[];           // BB*CC*MM = 10240 floats ([b][c][l] order)
    int kb = blockIdx.x;
    int t = threadIdx.x;
    const float* chunk = Gt + (size_t)kb * (BB*CC*MM);
    for (int j = t; j < BB*CC*MM; j += 256) gl[j] = chunk[j];
    __syncthreads();
    int o = t & 63, g = t >> 6;
    int b0 = 2*g, b1 = 2*g + 1;
    const float* wp; int kk;
    if (kb < MM) { wp = w1; kk = kb; } else { wp = w2; kk = kb - MM; }
    float a0[MM], a1[MM];
    #pragma unroll
    for (int l = 0; l < MM; ++l) { a0[l] = 0.f; a1[l] = 0.f; }
    for (int i = 0; i < CC; ++i) {
        const float4* wr4 = reinterpret_cast<const float4*>(wp + ((size_t)(i*CC + o)*MM + kk)*MM);
        const float4* g04 = reinterpret_cast<const float4*>(&gl[(b0*CC + i)*MM]);
        const float4* g14 = reinterpret_cast<const float4*>(&gl[(b1*CC + i)*MM]);
        #pragma unroll
        for (int l4 = 0; l4 < MM/4; ++l4) {
            float4 wv = wr4[l4];
            float4 gv0 = g04[l4];
            float4 gv1 = g14[l4];
            a0[4*l4+0] += wv.x*gv0.x; a0[4*l4+1] += wv.y*gv0.y;
            a0[4*l4+2] += wv.z*gv0.z; a0[4*l4+3] += wv.w*gv0.w;
            a1[4*l4+0] += wv.x*gv1.x; a1[4*l4+1] += wv.y*gv1.y;
            a1[4*l4+2] += wv.z*gv1.z; a1[4*l4+3] += wv.w*gv1.w;
        }
    }
    #pragma unroll
    for (int l = 0; l < MM; ++l) {
        S[((size_t)(b0*NKK + kb)*MM + l)*CC + o] = a0[l];   // coalesced in o
        S[((size_t)(b1*NKK + kb)*MM + l)*CC + o] = a1[l];
    }
}

// ---------------------------------------------------------------------------
// Inverse stage 1: U[b,p,l,o] = sum_k BkT[k,p] * S[b,k,l,o].
// Block=(b,p); wave w handles l = w + 4j (j=0..4); lane = o. No LDS.
__global__ __launch_bounds__(256, 2) void k_inv1(const float* __restrict__ S, const float* __restrict__ BkT,
                                                 float* __restrict__ U) {
    int b = blockIdx.x >> 8, p = blockIdx.x & 255;
    int o = threadIdx.x & 63, w = threadIdx.x >> 6;
    float acc[5];
    #pragma unroll
    for (int j = 0; j < 5; ++j) acc[j] = 0.f;
    for (int k = 0; k < NKK; ++k) {
        float bk = BkT[k*NN + p];                       // wave-uniform
        const float* sb = S + ((size_t)(b*NKK + k)*MM + w)*CC + o;
        #pragma unroll
        for (int j = 0; j < 5; ++j) acc[j] += bk * sb[(size_t)(4*j)*CC];
    }
    float* ub = U + ((size_t)(b*NN + p)*MM + w)*CC + o;
    #pragma unroll
    for (int j = 0; j < 5; ++j) ub[(size_t)(4*j)*CC] = acc[j];
}

// ---------------------------------------------------------------------------
// Combine IN PLACE, ONE row per block, NO LDS:
//   h[b,o,p,q] = tanh( conv(h)[o] + cb[o] + sum_l U[b,p,l,o]*BlT[l,q] )
// Weights/U rows wave-uniform -> scalar pipe. ONE acc[64] per thread —
// round-7 lesson: two 64-float register arrays get demoted to scratch
// (VGPR_Count=80 < live set), one promotes (r6: VGPR=92).
__global__ __launch_bounds__(256, 2) void k_combine(float* h, const float* __restrict__ U,
                                                    const float* __restrict__ BlT, const float* __restrict__ cwt,
                                                    const float* __restrict__ cb) {
    int b = blockIdx.x >> 8, p = blockIdx.x & 255;
    int q = threadIdx.x;
    float acc[CC];
    #pragma unroll
    for (int o = 0; o < CC; ++o) acc[o] = cb[o];
    float* hb = h + (size_t)b*CC*PLANE + (size_t)p*NN + q;
    #pragma unroll 4
    for (int i = 0; i < CC; ++i) {
        float hv = hb[(size_t)i*PLANE];
        const float* wr = &cwt[i*CC];                   // wave-uniform -> s_load
        #pragma unroll
        for (int o = 0; o < CC; ++o) acc[o] += wr[o]*hv;
    }
    const float* ub = U + ((size_t)(b*NN + p)*MM)*CC;
    #pragma unroll 2
    for (int l = 0; l < MM; ++l) {
        float blv = BlT[l*NN + q];
        const float* ur = ub + (size_t)l*CC;            // wave-uniform row
        #pragma unroll
        for (int o = 0; o < CC; ++o) acc[o] += ur[o]*blv;
    }
    #pragma unroll
    for (int o = 0; o < CC; ++o) hb[(size_t)o*PLANE] = fast_tanh(acc[o]);
}

// ---------------------------------------------------------------------------
// Last layer, fused-linear + wave-split + readfirstlane (r7 fix CONFIRMED
// r10: SGPR 32->112, dur 846->312, VALUBusy 55%). ROUND-10 tweak: Phase-B
// j-loop unroll 4->8 — doubles strided h-loads in flight (MLP); VGPR
// headroom large (44 used). Summation order per accumulator unchanged.
__global__ __launch_bounds__(256) void k_fuse_w(const float* __restrict__ cwt, const float* __restrict__ cb,
        const float* __restrict__ w1, const float* __restrict__ b1,
        float* __restrict__ Wt, float* __restrict__ bt) {
    int idx = blockIdx.x*256 + threadIdx.x;     // [0, CC*FCD)
    int j = idx >> 7, f = idx & 127;
    float s = 0.f;
    #pragma unroll 8
    for (int i = 0; i < CC; ++i) s += cwt[j*CC + i] * w1[i*FCD + f];
    Wt[idx] = s;
    if (idx < FCD) {
        float sb = b1[idx];
        for (int i = 0; i < CC; ++i) sb += cb[i] * w1[i*FCD + idx];
        bt[idx] = sb;
    }
}

__global__ __launch_bounds__(256, 4) void k_fc_last(const float* __restrict__ h, const float* __restrict__ U,
        const float* __restrict__ BlT, const float* __restrict__ w1,
        const float* __restrict__ Wt, const float* __restrict__ bt,
        const float* __restrict__ w2, const float* __restrict__ b2, float* __restrict__ out) {
    __shared__ float ul[MM*FCD];                // 20x128 = 10 KB
    __shared__ float red[4][64];                // wave partials, 1 KB
    int qc = blockIdx.x & 3;
    int p  = (blockIdx.x >> 2) & 255;
    int b  = blockIdx.x >> 10;
    int lane = threadIdx.x & 63;
    // readfirstlane: provably wave-uniform; forces SGPR residency so the
    // compiler emits s_load for weight rows (round-7 lesson, r10-confirmed).
    int w  = __builtin_amdgcn_readfirstlane(threadIdx.x >> 6);
    int q  = qc*64 + lane;
    int f0 = w*32;
    // Phase A: ul[l][f] = sum_o U[b,p,l,o] * w1[o,f]  (cooperative, 640 FMA/thr)
    const float* ub = U + ((size_t)(b*NN + p)*MM)*CC;
    for (int it = 0; it < MM*FCD/256; ++it) {
        int idx = it*256 + threadIdx.x;
        int l = __builtin_amdgcn_readfirstlane(idx >> 7);   // wave-uniform row
        int f = idx & 127;
        const float* ur = ub + l*CC;            // uniform row -> s_load
        float s = 0.f;
        #pragma unroll 8
        for (int o = 0; o < CC; ++o) s += ur[o] * w1[o*FCD + f];   // w1 coalesced in f
        ul[idx] = s;
    }
    __syncthreads();
    // Phase B: each thread = (pixel q, f-chunk w). h read ONCE per pixel.
    const float* hb = h + (size_t)b*CC*PLANE + (size_t)p*NN + q;
    float a[32];
    #pragma unroll
    for (int f = 0; f < 32; ++f) a[f] = bt[f0 + f];
    #pragma unroll 8
    for (int j = 0; j < CC; ++j) {
        float hv = hb[(size_t)j*PLANE];         // coalesced across lanes; 8 in flight
        const float* wr = &Wt[j*FCD + f0];      // uniform -> s_load
        #pragma unroll
        for (int f = 0; f < 32; ++f) a[f] += hv*wr[f];
    }
    #pragma unroll 2
    for (int l = 0; l < MM; ++l) {
        float blv = BlT[l*NN + q];
        const float* ur = &ul[l*FCD + f0];      // uniform LDS row -> broadcast
        #pragma unroll
        for (int f = 0; f < 32; ++f) a[f] += blv*ur[f];
    }
    float pv = 0.f;
    #pragma unroll
    for (int f = 0; f < 32; ++f) pv += fast_tanh(a[f]) * w2[f0 + f];
    red[w][lane] = pv;
    __syncthreads();
    if (w == 0) {
        float ov = b2[0] + red[0][lane] + red[1][lane] + red[2][lane] + red[3][lane];
        out[((size_t)(b*NN + p))*NN + q] = ov;
    }
}

// ---------------------------------------------------------------------------
extern "C" void kernel_launch(void* const* d_in, const int* in_sizes, int n_in,
                              void* d_out, int out_size, void* d_ws, size_t ws_size,
                              hipStream_t stream) {
    const float* x      = (const float*)d_in[0];
    const float* fc0_w  = (const float*)d_in[1];
    const float* fc0_b  = (const float*)d_in[2];
    const float* sp_w1  = (const float*)d_in[3];
    const float* sp_w2  = (const float*)d_in[4];
    const float* conv_w = (const float*)d_in[5];
    const float* conv_b = (const float*)d_in[6];
    const float* fc1_w  = (const float*)d_in[7];
    const float* fc1_b  = (const float*)d_in[8];
    const float* fc2_w  = (const float*)d_in[9];
    const float* fc2_b  = (const float*)d_in[10];

    float* ws = (float*)d_ws;
    const size_t HSZ = (size_t)BB*CC*PLANE;           // 33,554,432 floats (134.2 MB)
    float* hA  = ws;
    float* Gt  = hA + HSZ;                            // NKK*BB*CC*MM = 409,600
    float* S   = Gt + (size_t)NKK*BB*CC*MM;           // BB*NKK*MM*CC = 409,600
    float* U   = S  + (size_t)BB*NKK*MM*CC;           // BB*NN*MM*CC  = 2,621,440
    float* FlT = U  + (size_t)BB*NN*MM*CC;            // NN*MM   =  5,120
    float* FkT = FlT + NN*MM;                         // NN*NKK  = 10,240
    float* BkT = FkT + NN*NKK;                        // NKK*NN  = 10,240
    float* BlT = BkT + NKK*NN;                        // MM*NN   =  5,120
    float* CwT = BlT + MM*NN;                         // NLAY*CC*CC = 12,288
    float* Wt  = CwT + NLAY*CC*CC;                    // CC*FCD  =  8,192
    float* bt  = Wt  + CC*FCD;                        // FCD     =    128
    // total = 37,046,400 floats = 148.2 MB of workspace

    k_basis<<<1, 256, 0, stream>>>(FlT, FkT, BkT, BlT, CwT, conv_w);
    k_fc0<<<BB*NN, 256, 0, stream>>>(x, fc0_w, fc0_b, hA);
    // Layer-constant fused fc weights for the last layer (off critical path).
    k_fuse_w<<<CC*FCD/256, 256, 0, stream>>>(CwT + (NLAY-1)*CC*CC, conv_b + (NLAY-1)*CC,
                                             fc1_w, fc1_b, Wt, bt);

    for (int lay = 0; lay < NLAY; ++lay) {
        const float* w1 = sp_w1 + (size_t)lay*CC*CC*MM*MM;
        const float* w2 = sp_w2 + (size_t)lay*CC*CC*MM*MM;
        k_fwd<<<BB*CC*2, 256, 0, stream>>>(hA, FkT, FlT, Gt);
        k_spec<<<NKK, 256, BB*CC*MM*sizeof(float), stream>>>(Gt, w1, w2, S);
        k_inv1<<<BB*NN, 256, 0, stream>>>(S, BkT, U);
        if (lay != NLAY-1) {
            k_combine<<<BB*NN, 256, 0, stream>>>(
                hA, U, BlT, CwT + lay*CC*CC, conv_b + lay*CC);
        } else {
            k_fc_last<<<BB*NN*4, 256, 0, stream>>>(
                hA, U, BlT, fc1_w, Wt, bt, fc2_w, fc2_b, (float*)d_out);
        }
    }
}

// Round 12
// 1069.636 us; speedup vs baseline: 1.5315x; 1.0031x over previous
//
#include <hip/hip_runtime.h>
#include <math.h>

#define BB    8
#define CC    64
#define NN    256
#define MM    20      // retained modes per axis
#define NKK   40      // retained row-modes: {0..19} U {236..255}
#define NLAY  3
#define FCD   128
#define PLANE (NN*NN)

// Fast tanh: clamp + exp-based. v_exp_f32/v_rcp_f32, ~1e-7 abs error, no branches.
__device__ __forceinline__ float fast_tanh(float x) {
    float xc = fminf(fmaxf(x, -15.f), 15.f);
    float e = __expf(2.f * xc);
    return (e - 1.f) / (e + 1.f);
}

// ---------------------------------------------------------------------------
// Basis precompute (double precision on device; tiny).
__global__ __launch_bounds__(256) void k_basis(float* __restrict__ FlT, float* __restrict__ FkT,
                                               float* __restrict__ BkT, float* __restrict__ BlT,
                                               float* __restrict__ CwT, const float* __restrict__ conv_w) {
    int t = threadIdx.x;
    const double PI = 3.14159265358979323846;
    for (int j = t; j < NN*MM; j += 256) {
        int y = j / MM, l = j % MM;
        double g = (y == 0 || y == NN-1) ? 1.0 : 2.0;
        FlT[j] = (float)(g * cos(PI * (double)(l*y) / (double)(NN-1)));
    }
    for (int j = t; j < NN*NKK; j += 256) {
        int x = j / NKK, k = j % NKK;
        int rk = (k < MM) ? k : (NN - NKK + k);
        double g = (x == 0 || x == NN-1) ? 1.0 : 2.0;
        FkT[j] = (float)(g * cos(PI * (double)(rk*x) / (double)(NN-1)));
    }
    for (int j = t; j < NKK*NN; j += 256) {
        int k = j / NN, p = j % NN;
        int rk = (k < MM) ? k : (NN - NKK + k);
        double g = (rk == 0 || rk == NN-1) ? 1.0 : 2.0;
        BkT[j] = (float)(g * cos(PI * (double)(rk*p) / (double)(NN-1)));
    }
    for (int j = t; j < MM*NN; j += 256) {
        int l = j / NN, q = j % NN;
        double g = (l == 0) ? 1.0 : 2.0;
        BlT[j] = (float)(g * cos(PI * (double)(q*l) / (double)(NN-1)));
    }
    for (int j = t; j < NLAY*CC*CC; j += 256) {
        int lay = j / (CC*CC), r = j % (CC*CC);
        int i = r / CC, o = r % CC;
        CwT[j] = conv_w[lay*CC*CC + o*CC + i];
    }
}

// ---------------------------------------------------------------------------
// fc0: h[b,c,p,q] = sum_d x[b,p,q,d]*w[d,c] + bias[c].  Block=(b,p), thread=q.
__global__ __launch_bounds__(256) void k_fc0(const float* __restrict__ xin, const float* __restrict__ w,
                                             const float* __restrict__ bias, float* __restrict__ h) {
    __shared__ float xs[NN*3];
    int b = blockIdx.x >> 8, p = blockIdx.x & 255, q = threadIdx.x;
    size_t rowbase = ((size_t)(b*NN + p)*NN) * 3;
    for (int j = q; j < NN*3; j += 256) xs[j] = xin[rowbase + j];
    __syncthreads();
    float v0 = xs[q*3+0], v1 = xs[q*3+1], v2 = xs[q*3+2];
    size_t obase = (size_t)b*CC*PLANE + (size_t)p*NN + q;
    #pragma unroll 8
    for (int c = 0; c < CC; ++c) {
        float hv = bias[c] + v0*w[c] + v1*w[CC+c] + v2*w[2*CC+c];
        h[obase + (size_t)c*PLANE] = hv;
    }
}

// ---------------------------------------------------------------------------
// Forward truncated DCT, ROUND-10 K-SPLIT (kept: total dropped 1123->1073).
__global__ __launch_bounds__(256, 4) void k_fwd(const float* __restrict__ h, const float* __restrict__ FkT,
                                                const float* __restrict__ FlT, float* __restrict__ Gt) {
    __shared__ float P[MM][NN+1];           // 20 x 257 floats = 20.6 KB
    int plane = blockIdx.x >> 1;            // b*CC + c
    int g = blockIdx.x & 1;                 // k-group: rows [20g, 20g+20)
    int t = threadIdx.x;
    const float* hp = h + (size_t)plane * PLANE;
    const float* fk = FkT + g*MM;           // this group's 20 columns of FkT rows
    float acc[MM];
    #pragma unroll
    for (int k = 0; k < MM; ++k) acc[k] = 0.f;
    #pragma unroll 4
    for (int x = 0; x < NN; ++x) {
        float hv = hp[x*NN + t];
        const float* fr = &fk[x*NKK];       // wave-uniform address -> s_load
        #pragma unroll
        for (int k = 0; k < MM; ++k) acc[k] += fr[k] * hv;
    }
    #pragma unroll
    for (int k = 0; k < MM; ++k) P[k][t] = acc[k];
    __syncthreads();
    int b = plane >> 6, c = plane & 63;
    for (int j = t; j < MM*MM; j += 256) {  // 400 outputs, 2 iters
        int kk = j / MM, l = j % MM;
        float a = 0.f;
        for (int y = 0; y < NN; ++y) a += P[kk][y] * FlT[y*MM + l];
        Gt[((size_t)((g*MM + kk)*BB + b)*CC + c)*MM + l] = a;
    }
}

// ---------------------------------------------------------------------------
// Spectral mode-mix: S[b,k,l,o] = sum_i G[b,i,kb,l] * w[i,o,kk,l].
// S layout [b][k][l][o] (o contiguous) for coalesced k_inv1 / wave-uniform U rows.
__global__ __launch_bounds__(256, 2) void k_spec(const float* __restrict__ Gt, const float* __restrict__ w1,
                                                 const float* __restrict__ w2, float* __restrict__ S) {
    extern __shared__ float gl[];           // BB*CC*MM = 10240 floats ([b][c][l] order)
    int kb = blockIdx.x;
    int t = threadIdx.x;
    const float* chunk = Gt + (size_t)kb * (BB*CC*MM);
    for (int j = t; j < BB*CC*MM; j += 256) gl[j] = chunk[j];
    __syncthreads();
    int o = t & 63, g = t >> 6;
    int b0 = 2*g, b1 = 2*g + 1;
    const float* wp; int kk;
    if (kb < MM) { wp = w1; kk = kb; } else { wp = w2; kk = kb - MM; }
    float a0[MM], a1[MM];
    #pragma unroll
    for (int l = 0; l < MM; ++l) { a0[l] = 0.f; a1[l] = 0.f; }
    for (int i = 0; i < CC; ++i) {
        const float4* wr4 = reinterpret_cast<const float4*>(wp + ((size_t)(i*CC + o)*MM + kk)*MM);
        const float4* g04 = reinterpret_cast<const float4*>(&gl[(b0*CC + i)*MM]);
        const float4* g14 = reinterpret_cast<const float4*>(&gl[(b1*CC + i)*MM]);
        #pragma unroll
        for (int l4 = 0; l4 < MM/4; ++l4) {
            float4 wv = wr4[l4];
            float4 gv0 = g04[l4];
            float4 gv1 = g14[l4];
            a0[4*l4+0] += wv.x*gv0.x; a0[4*l4+1] += wv.y*gv0.y;
            a0[4*l4+2] += wv.z*gv0.z; a0[4*l4+3] += wv.w*gv0.w;
            a1[4*l4+0] += wv.x*gv1.x; a1[4*l4+1] += wv.y*gv1.y;
            a1[4*l4+2] += wv.z*gv1.z; a1[4*l4+3] += wv.w*gv1.w;
        }
    }
    #pragma unroll
    for (int l = 0; l < MM; ++l) {
        S[((size_t)(b0*NKK + kb)*MM + l)*CC + o] = a0[l];   // coalesced in o
        S[((size_t)(b1*NKK + kb)*MM + l)*CC + o] = a1[l];
    }
}

// ---------------------------------------------------------------------------
// Inverse stage 1: U[b,p,l,o] = sum_k BkT[k,p] * S[b,k,l,o].
// Block=(b,p); wave w handles l = w + 4j (j=0..4); lane = o. No LDS.
__global__ __launch_bounds__(256, 2) void k_inv1(const float* __restrict__ S, const float* __restrict__ BkT,
                                                 float* __restrict__ U) {
    int b = blockIdx.x >> 8, p = blockIdx.x & 255;
    int o = threadIdx.x & 63, w = threadIdx.x >> 6;
    float acc[5];
    #pragma unroll
    for (int j = 0; j < 5; ++j) acc[j] = 0.f;
    for (int k = 0; k < NKK; ++k) {
        float bk = BkT[k*NN + p];                       // wave-uniform
        const float* sb = S + ((size_t)(b*NKK + k)*MM + w)*CC + o;
        #pragma unroll
        for (int j = 0; j < 5; ++j) acc[j] += bk * sb[(size_t)(4*j)*CC];
    }
    float* ub = U + ((size_t)(b*NN + p)*MM + w)*CC + o;
    #pragma unroll
    for (int j = 0; j < 5; ++j) ub[(size_t)(4*j)*CC] = acc[j];
}

// ---------------------------------------------------------------------------
// Combine IN PLACE — ROUND-11 WAVE-SPLIT (the r10-confirmed k_fc_last recipe
// applied to the last big acc[64] kernel): block = (b, p, q-chunk of 64);
// 4 waves x 64 lanes; wave w owns o-chunk [16w,16w+16), lane owns pixel q.
// acc[64]->acc[16] (VGPR ~92->~40, more waves/SIMD), grid 2048->8192 (4x
// TLP to hide the 64 strided h-plane loads). readfirstlane(w) keeps cwt/U
// row addressing on the scalar pipe (round-7 lesson, applied preemptively).
// In-place safety: __syncthreads between last h-read (consumed by acc) and
// first h-write; q-columns disjoint across blocks. Per-output summation
// order identical (i ascending, then l ascending) -> bit-identical.
__global__ __launch_bounds__(256, 4) void k_combine(float* h, const float* __restrict__ U,
                                                    const float* __restrict__ BlT, const float* __restrict__ cwt,
                                                    const float* __restrict__ cb) {
    int qc = blockIdx.x & 3;
    int p  = (blockIdx.x >> 2) & 255;
    int b  = blockIdx.x >> 10;
    int lane = threadIdx.x & 63;
    int w = __builtin_amdgcn_readfirstlane(threadIdx.x >> 6);
    int q = qc*64 + lane;
    int o0 = w*16;
    float acc[16];
    #pragma unroll
    for (int oo = 0; oo < 16; ++oo) acc[oo] = cb[o0 + oo];
    float* hb = h + (size_t)b*CC*PLANE + (size_t)p*NN + q;
    #pragma unroll 4
    for (int i = 0; i < CC; ++i) {
        float hv = hb[(size_t)i*PLANE];                 // coalesced; waves share rows via L1
        const float* wr = &cwt[i*CC + o0];              // uniform -> s_load
        #pragma unroll
        for (int oo = 0; oo < 16; ++oo) acc[oo] += wr[oo]*hv;
    }
    const float* ub = U + ((size_t)(b*NN + p)*MM)*CC + o0;
    #pragma unroll 4
    for (int l = 0; l < MM; ++l) {
        float blv = BlT[l*NN + q];
        const float* ur = ub + (size_t)l*CC;            // uniform row -> s_load
        #pragma unroll
        for (int oo = 0; oo < 16; ++oo) acc[oo] += ur[oo]*blv;
    }
    __syncthreads();    // all waves' h reads drained before any in-place write
    #pragma unroll
    for (int oo = 0; oo < 16; ++oo) hb[(size_t)(o0 + oo)*PLANE] = fast_tanh(acc[oo]);
}

// ---------------------------------------------------------------------------
// Last layer, fused-linear + wave-split + readfirstlane (r10: SGPR 112,
// 312 µs, VALUBusy 55%). FROZEN this round — two tweaks (LDS staging r3,
// unroll-8 r10) failed to move it; its stall needs disasm evidence, not
// another guess.
__global__ __launch_bounds__(256) void k_fuse_w(const float* __restrict__ cwt, const float* __restrict__ cb,
        const float* __restrict__ w1, const float* __restrict__ b1,
        float* __restrict__ Wt, float* __restrict__ bt) {
    int idx = blockIdx.x*256 + threadIdx.x;     // [0, CC*FCD)
    int j = idx >> 7, f = idx & 127;
    float s = 0.f;
    #pragma unroll 8
    for (int i = 0; i < CC; ++i) s += cwt[j*CC + i] * w1[i*FCD + f];
    Wt[idx] = s;
    if (idx < FCD) {
        float sb = b1[idx];
        for (int i = 0; i < CC; ++i) sb += cb[i] * w1[i*FCD + idx];
        bt[idx] = sb;
    }
}

__global__ __launch_bounds__(256, 4) void k_fc_last(const float* __restrict__ h, const float* __restrict__ U,
        const float* __restrict__ BlT, const float* __restrict__ w1,
        const float* __restrict__ Wt, const float* __restrict__ bt,
        const float* __restrict__ w2, const float* __restrict__ b2, float* __restrict__ out) {
    __shared__ float ul[MM*FCD];                // 20x128 = 10 KB
    __shared__ float red[4][64];                // wave partials, 1 KB
    int qc = blockIdx.x & 3;
    int p  = (blockIdx.x >> 2) & 255;
    int b  = blockIdx.x >> 10;
    int lane = threadIdx.x & 63;
    int w  = __builtin_amdgcn_readfirstlane(threadIdx.x >> 6);
    int q  = qc*64 + lane;
    int f0 = w*32;
    // Phase A: ul[l][f] = sum_o U[b,p,l,o] * w1[o,f]  (cooperative, 640 FMA/thr)
    const float* ub = U + ((size_t)(b*NN + p)*MM)*CC;
    for (int it = 0; it < MM*FCD/256; ++it) {
        int idx = it*256 + threadIdx.x;
        int l = __builtin_amdgcn_readfirstlane(idx >> 7);   // wave-uniform row
        int f = idx & 127;
        const float* ur = ub + l*CC;            // uniform row -> s_load
        float s = 0.f;
        #pragma unroll 8
        for (int o = 0; o < CC; ++o) s += ur[o] * w1[o*FCD + f];   // w1 coalesced in f
        ul[idx] = s;
    }
    __syncthreads();
    // Phase B: each thread = (pixel q, f-chunk w). h read ONCE per pixel.
    const float* hb = h + (size_t)b*CC*PLANE + (size_t)p*NN + q;
    float a[32];
    #pragma unroll
    for (int f = 0; f < 32; ++f) a[f] = bt[f0 + f];
    #pragma unroll 8
    for (int j = 0; j < CC; ++j) {
        float hv = hb[(size_t)j*PLANE];         // coalesced across lanes
        const float* wr = &Wt[j*FCD + f0];      // uniform -> s_load
        #pragma unroll
        for (int f = 0; f < 32; ++f) a[f] += hv*wr[f];
    }
    #pragma unroll 2
    for (int l = 0; l < MM; ++l) {
        float blv = BlT[l*NN + q];
        const float* ur = &ul[l*FCD + f0];      // uniform LDS row -> broadcast
        #pragma unroll
        for (int f = 0; f < 32; ++f) a[f] += blv*ur[f];
    }
    float pv = 0.f;
    #pragma unroll
    for (int f = 0; f < 32; ++f) pv += fast_tanh(a[f]) * w2[f0 + f];
    red[w][lane] = pv;
    __syncthreads();
    if (w == 0) {
        float ov = b2[0] + red[0][lane] + red[1][lane] + red[2][lane] + red[3][lane];
        out[((size_t)(b*NN + p))*NN + q] = ov;
    }
}

// ---------------------------------------------------------------------------
extern "C" void kernel_launch(void* const* d_in, const int* in_sizes, int n_in,
                              void* d_out, int out_size, void* d_ws, size_t ws_size,
                              hipStream_t stream) {
    const float* x      = (const float*)d_in[0];
    const float* fc0_w  = (const float*)d_in[1];
    const float* fc0_b  = (const float*)d_in[2];
    const float* sp_w1  = (const float*)d_in[3];
    const float* sp_w2  = (const float*)d_in[4];
    const float* conv_w = (const float*)d_in[5];
    const float* conv_b = (const float*)d_in[6];
    const float* fc1_w  = (const float*)d_in[7];
    const float* fc1_b  = (const float*)d_in[8];
    const float* fc2_w  = (const float*)d_in[9];
    const float* fc2_b  = (const float*)d_in[10];

    float* ws = (float*)d_ws;
    const size_t HSZ = (size_t)BB*CC*PLANE;           // 33,554,432 floats (134.2 MB)
    float* hA  = ws;
    float* Gt  = hA + HSZ;                            // NKK*BB*CC*MM = 409,600
    float* S   = Gt + (size_t)NKK*BB*CC*MM;           // BB*NKK*MM*CC = 409,600
    float* U   = S  + (size_t)BB*NKK*MM*CC;           // BB*NN*MM*CC  = 2,621,440
    float* FlT = U  + (size_t)BB*NN*MM*CC;            // NN*MM   =  5,120
    float* FkT = FlT + NN*MM;                         // NN*NKK  = 10,240
    float* BkT = FkT + NN*NKK;                        // NKK*NN  = 10,240
    float* BlT = BkT + NKK*NN;                        // MM*NN   =  5,120
    float* CwT = BlT + MM*NN;                         // NLAY*CC*CC = 12,288
    float* Wt  = CwT + NLAY*CC*CC;                    // CC*FCD  =  8,192
    float* bt  = Wt  + CC*FCD;                        // FCD     =    128
    // total = 37,046,400 floats = 148.2 MB of workspace

    k_basis<<<1, 256, 0, stream>>>(FlT, FkT, BkT, BlT, CwT, conv_w);
    k_fc0<<<BB*NN, 256, 0, stream>>>(x, fc0_w, fc0_b, hA);
    // Layer-constant fused fc weights for the last layer (off critical path).
    k_fuse_w<<<CC*FCD/256, 256, 0, stream>>>(CwT + (NLAY-1)*CC*CC, conv_b + (NLAY-1)*CC,
                                             fc1_w, fc1_b, Wt, bt);

    for (int lay = 0; lay < NLAY; ++lay) {
        const float* w1 = sp_w1 + (size_t)lay*CC*CC*MM*MM;
        const float* w2 = sp_w2 + (size_t)lay*CC*CC*MM*MM;
        k_fwd<<<BB*CC*2, 256, 0, stream>>>(hA, FkT, FlT, Gt);
        k_spec<<<NKK, 256, BB*CC*MM*sizeof(float), stream>>>(Gt, w1, w2, S);
        k_inv1<<<BB*NN, 256, 0, stream>>>(S, BkT, U);
        if (lay != NLAY-1) {
            k_combine<<<BB*NN*4, 256, 0, stream>>>(
                hA, U, BlT, CwT + lay*CC*CC, conv_b + lay*CC);
        } else {
            k_fc_last<<<BB*NN*4, 256, 0, stream>>>(
                hA, U, BlT, fc1_w, Wt, bt, fc2_w, fc2_b, (float*)d_out);
        }
    }
}

// Round 14
// 993.310 us; speedup vs baseline: 1.6492x; 1.0768x over previous
//
#include <hip/hip_runtime.h>
#include <math.h>

#define BB    8
#define CC    64
#define NN    256
#define MM    20      // retained modes per axis
#define NKK   40      // retained row-modes: {0..19} U {236..255}
#define NLAY  3
#define FCD   128
#define PLANE (NN*NN)

// Fast tanh: clamp + exp-based. v_exp_f32/v_rcp_f32, ~1e-7 abs error, no branches.
__device__ __forceinline__ float fast_tanh(float x) {
    float xc = fminf(fmaxf(x, -15.f), 15.f);
    float e = __expf(2.f * xc);
    return (e - 1.f) / (e + 1.f);
}

// ---------------------------------------------------------------------------
// Basis precompute (double precision on device; tiny).
__global__ __launch_bounds__(256) void k_basis(float* __restrict__ FlT, float* __restrict__ FkT,
                                               float* __restrict__ BkT, float* __restrict__ BlT,
                                               float* __restrict__ CwT, const float* __restrict__ conv_w) {
    int t = threadIdx.x;
    const double PI = 3.14159265358979323846;
    for (int j = t; j < NN*MM; j += 256) {
        int y = j / MM, l = j % MM;
        double g = (y == 0 || y == NN-1) ? 1.0 : 2.0;
        FlT[j] = (float)(g * cos(PI * (double)(l*y) / (double)(NN-1)));
    }
    for (int j = t; j < NN*NKK; j += 256) {
        int x = j / NKK, k = j % NKK;
        int rk = (k < MM) ? k : (NN - NKK + k);
        double g = (x == 0 || x == NN-1) ? 1.0 : 2.0;
        FkT[j] = (float)(g * cos(PI * (double)(rk*x) / (double)(NN-1)));
    }
    for (int j = t; j < NKK*NN; j += 256) {
        int k = j / NN, p = j % NN;
        int rk = (k < MM) ? k : (NN - NKK + k);
        double g = (rk == 0 || rk == NN-1) ? 1.0 : 2.0;
        BkT[j] = (float)(g * cos(PI * (double)(rk*p) / (double)(NN-1)));
    }
    for (int j = t; j < MM*NN; j += 256) {
        int l = j / NN, q = j % NN;
        double g = (l == 0) ? 1.0 : 2.0;
        BlT[j] = (float)(g * cos(PI * (double)(q*l) / (double)(NN-1)));
    }
    for (int j = t; j < NLAY*CC*CC; j += 256) {
        int lay = j / (CC*CC), r = j % (CC*CC);
        int i = r / CC, o = r % CC;
        CwT[j] = conv_w[lay*CC*CC + o*CC + i];
    }
}

// ---------------------------------------------------------------------------
// fc0: h[b,c,p,q] = sum_d x[b,p,q,d]*w[d,c] + bias[c].  Block=(b,p), thread=q.
__global__ __launch_bounds__(256) void k_fc0(const float* __restrict__ xin, const float* __restrict__ w,
                                             const float* __restrict__ bias, float* __restrict__ h) {
    __shared__ float xs[NN*3];
    int b = blockIdx.x >> 8, p = blockIdx.x & 255, q = threadIdx.x;
    size_t rowbase = ((size_t)(b*NN + p)*NN) * 3;
    for (int j = q; j < NN*3; j += 256) xs[j] = xin[rowbase + j];
    __syncthreads();
    float v0 = xs[q*3+0], v1 = xs[q*3+1], v2 = xs[q*3+2];
    size_t obase = (size_t)b*CC*PLANE + (size_t)p*NN + q;
    #pragma unroll 8
    for (int c = 0; c < CC; ++c) {
        float hv = bias[c] + v0*w[c] + v1*w[CC+c] + v2*w[2*CC+c];
        h[obase + (size_t)c*PLANE] = hv;
    }
}

// ---------------------------------------------------------------------------
// Forward truncated DCT, ROUND-10 K-SPLIT (kept: total dropped 1123->1073).
__global__ __launch_bounds__(256, 4) void k_fwd(const float* __restrict__ h, const float* __restrict__ FkT,
                                                const float* __restrict__ FlT, float* __restrict__ Gt) {
    __shared__ float P[MM][NN+1];           // 20 x 257 floats = 20.6 KB
    int plane = blockIdx.x >> 1;            // b*CC + c
    int g = blockIdx.x & 1;                 // k-group: rows [20g, 20g+20)
    int t = threadIdx.x;
    const float* hp = h + (size_t)plane * PLANE;
    const float* fk = FkT + g*MM;           // this group's 20 columns of FkT rows
    float acc[MM];
    #pragma unroll
    for (int k = 0; k < MM; ++k) acc[k] = 0.f;
    #pragma unroll 4
    for (int x = 0; x < NN; ++x) {
        float hv = hp[x*NN + t];
        const float* fr = &fk[x*NKK];       // wave-uniform address -> s_load
        #pragma unroll
        for (int k = 0; k < MM; ++k) acc[k] += fr[k] * hv;
    }
    #pragma unroll
    for (int k = 0; k < MM; ++k) P[k][t] = acc[k];
    __syncthreads();
    int b = plane >> 6, c = plane & 63;
    for (int j = t; j < MM*MM; j += 256) {  // 400 outputs, 2 iters
        int kk = j / MM, l = j % MM;
        float a = 0.f;
        for (int y = 0; y < NN; ++y) a += P[kk][y] * FlT[y*MM + l];
        Gt[((size_t)((g*MM + kk)*BB + b)*CC + c)*MM + l] = a;
    }
}

// ---------------------------------------------------------------------------
// Spectral mode-mix: S[b,k,l,o] = sum_i G[b,i,kb,l] * w[i,o,kk,l].
// S layout [b][k][l][o] (o contiguous) for coalesced k_inv1 / wave-uniform U rows.
__global__ __launch_bounds__(256, 2) void k_spec(const float* __restrict__ Gt, const float* __restrict__ w1,
                                                 const float* __restrict__ w2, float* __restrict__ S) {
    extern __shared__ float gl[];           // BB*CC*MM = 10240 floats ([b][c][l] order)
    int kb = blockIdx.x;
    int t = threadIdx.x;
    const float* chunk = Gt + (size_t)kb * (BB*CC*MM);
    for (int j = t; j < BB*CC*MM; j += 256) gl[j] = chunk[j];
    __syncthreads();
    int o = t & 63, g = t >> 6;
    int b0 = 2*g, b1 = 2*g + 1;
    const float* wp; int kk;
    if (kb < MM) { wp = w1; kk = kb; } else { wp = w2; kk = kb - MM; }
    float a0[MM], a1[MM];
    #pragma unroll
    for (int l = 0; l < MM; ++l) { a0[l] = 0.f; a1[l] = 0.f; }
    for (int i = 0; i < CC; ++i) {
        const float4* wr4 = reinterpret_cast<const float4*>(wp + ((size_t)(i*CC + o)*MM + kk)*MM);
        const float4* g04 = reinterpret_cast<const float4*>(&gl[(b0*CC + i)*MM]);
        const float4* g14 = reinterpret_cast<const float4*>(&gl[(b1*CC + i)*MM]);
        #pragma unroll
        for (int l4 = 0; l4 < MM/4; ++l4) {
            float4 wv = wr4[l4];
            float4 gv0 = g04[l4];
            float4 gv1 = g14[l4];
            a0[4*l4+0] += wv.x*gv0.x; a0[4*l4+1] += wv.y*gv0.y;
            a0[4*l4+2] += wv.z*gv0.z; a0[4*l4+3] += wv.w*gv0.w;
            a1[4*l4+0] += wv.x*gv1.x; a1[4*l4+1] += wv.y*gv1.y;
            a1[4*l4+2] += wv.z*gv1.z; a1[4*l4+3] += wv.w*gv1.w;
        }
    }
    #pragma unroll
    for (int l = 0; l < MM; ++l) {
        S[((size_t)(b0*NKK + kb)*MM + l)*CC + o] = a0[l];   // coalesced in o
        S[((size_t)(b1*NKK + kb)*MM + l)*CC + o] = a1[l];
    }
}

// ---------------------------------------------------------------------------
// Inverse stage 1: U[b,p,l,o] = sum_k BkT[k,p] * S[b,k,l,o].
// Block=(b,p); wave w handles l = w + 4j (j=0..4); lane = o. No LDS.
__global__ __launch_bounds__(256, 2) void k_inv1(const float* __restrict__ S, const float* __restrict__ BkT,
                                                 float* __restrict__ U) {
    int b = blockIdx.x >> 8, p = blockIdx.x & 255;
    int o = threadIdx.x & 63, w = threadIdx.x >> 6;
    float acc[5];
    #pragma unroll
    for (int j = 0; j < 5; ++j) acc[j] = 0.f;
    for (int k = 0; k < NKK; ++k) {
        float bk = BkT[k*NN + p];                       // wave-uniform
        const float* sb = S + ((size_t)(b*NKK + k)*MM + w)*CC + o;
        #pragma unroll
        for (int j = 0; j < 5; ++j) acc[j] += bk * sb[(size_t)(4*j)*CC];
    }
    float* ub = U + ((size_t)(b*NN + p)*MM + w)*CC + o;
    #pragma unroll
    for (int j = 0; j < 5; ++j) ub[(size_t)(4*j)*CC] = acc[j];
}

// ---------------------------------------------------------------------------
// Combine IN PLACE — ROUND-11 WAVE-SPLIT (kept: neutral in time, lower VGPR).
__global__ __launch_bounds__(256, 4) void k_combine(float* h, const float* __restrict__ U,
                                                    const float* __restrict__ BlT, const float* __restrict__ cwt,
                                                    const float* __restrict__ cb) {
    int qc = blockIdx.x & 3;
    int p  = (blockIdx.x >> 2) & 255;
    int b  = blockIdx.x >> 10;
    int lane = threadIdx.x & 63;
    int w = __builtin_amdgcn_readfirstlane(threadIdx.x >> 6);
    int q = qc*64 + lane;
    int o0 = w*16;
    float acc[16];
    #pragma unroll
    for (int oo = 0; oo < 16; ++oo) acc[oo] = cb[o0 + oo];
    float* hb = h + (size_t)b*CC*PLANE + (size_t)p*NN + q;
    #pragma unroll 4
    for (int i = 0; i < CC; ++i) {
        float hv = hb[(size_t)i*PLANE];                 // coalesced; waves share rows via L1
        const float* wr = &cwt[i*CC + o0];              // uniform -> s_load
        #pragma unroll
        for (int oo = 0; oo < 16; ++oo) acc[oo] += wr[oo]*hv;
    }
    const float* ub = U + ((size_t)(b*NN + p)*MM)*CC + o0;
    #pragma unroll 4
    for (int l = 0; l < MM; ++l) {
        float blv = BlT[l*NN + q];
        const float* ur = ub + (size_t)l*CC;            // uniform row -> s_load
        #pragma unroll
        for (int oo = 0; oo < 16; ++oo) acc[oo] += ur[oo]*blv;
    }
    __syncthreads();    // all waves' h reads drained before any in-place write
    #pragma unroll
    for (int oo = 0; oo < 16; ++oo) hb[(size_t)(o0 + oo)*PLANE] = fast_tanh(acc[oo]);
}

// ---------------------------------------------------------------------------
// ROUND-12 REVERT: last layer back to the round-2 monolith (measured 243 µs,
// VALUBusy 82% — best measured last-layer by 69 µs). The fused-linear
// rewrite (r4-r12) never beat it: 446 -> 243 -> 312 across three fix
// rounds. The monolith's AGPR round-trips are "wasted" VALU work that
// empirically HIDES the 64x strided h-load latency its 12K-FMA body
// generates. Ledger: rest-of-pipeline improved 815 -> 758 (k_fwd split),
// so best-measured combination = 758 + 243 ~= 1001 µs.
// fc1 i-loop FULLY unrolled (acc[i] constant-indexed — round-5 lesson);
// single acc[64] + a[8] register shape (round-7 lesson).
__global__ __launch_bounds__(256, 2) void k_combine_fc(const float* __restrict__ h, const float* __restrict__ U,
        const float* __restrict__ BlT, const float* __restrict__ cwt, const float* __restrict__ cb,
        const float* __restrict__ w1, const float* __restrict__ b1,
        const float* __restrict__ w2, const float* __restrict__ b2, float* __restrict__ out) {
    int b = blockIdx.x >> 8, p = blockIdx.x & 255;
    int q = threadIdx.x;
    float acc[CC];
    #pragma unroll
    for (int o = 0; o < CC; ++o) acc[o] = cb[o];
    const float* hb = h + (size_t)b*CC*PLANE + (size_t)p*NN + q;
    #pragma unroll 4
    for (int i = 0; i < CC; ++i) {
        float hv = hb[(size_t)i*PLANE];
        const float* wr = &cwt[i*CC];                   // wave-uniform -> s_load
        #pragma unroll
        for (int o = 0; o < CC; ++o) acc[o] += wr[o]*hv;
    }
    const float* ub = U + ((size_t)(b*NN + p)*MM)*CC;
    #pragma unroll 2
    for (int l = 0; l < MM; ++l) {
        float blv = BlT[l*NN + q];
        const float* ur = ub + (size_t)l*CC;
        #pragma unroll
        for (int o = 0; o < CC; ++o) acc[o] += ur[o]*blv;
    }
    // fc1 -> tanh -> fc2 on the in-register channel vector
    float ov = b2[0];
    const int FCH = 8;
    for (int f0 = 0; f0 < FCD; f0 += FCH) {
        float a[FCH];
        #pragma unroll
        for (int f = 0; f < FCH; ++f) a[f] = b1[f0 + f];
        #pragma unroll                                  // FULL unroll: acc[i] constant-indexed
        for (int i = 0; i < CC; ++i) {
            float hv = acc[i];
            const float* wr = &w1[i*FCD + f0];          // wave-uniform -> s_load
            #pragma unroll
            for (int f = 0; f < FCH; ++f) a[f] += hv*wr[f];
        }
        #pragma unroll
        for (int f = 0; f < FCH; ++f) ov += fast_tanh(a[f]) * w2[f0 + f];
    }
    out[(size_t)blockIdx.x*NN + q] = ov;
}

// ---------------------------------------------------------------------------
extern "C" void kernel_launch(void* const* d_in, const int* in_sizes, int n_in,
                              void* d_out, int out_size, void* d_ws, size_t ws_size,
                              hipStream_t stream) {
    const float* x      = (const float*)d_in[0];
    const float* fc0_w  = (const float*)d_in[1];
    const float* fc0_b  = (const float*)d_in[2];
    const float* sp_w1  = (const float*)d_in[3];
    const float* sp_w2  = (const float*)d_in[4];
    const float* conv_w = (const float*)d_in[5];
    const float* conv_b = (const float*)d_in[6];
    const float* fc1_w  = (const float*)d_in[7];
    const float* fc1_b  = (const float*)d_in[8];
    const float* fc2_w  = (const float*)d_in[9];
    const float* fc2_b  = (const float*)d_in[10];

    float* ws = (float*)d_ws;
    const size_t HSZ = (size_t)BB*CC*PLANE;           // 33,554,432 floats (134.2 MB)
    float* hA  = ws;
    float* Gt  = hA + HSZ;                            // NKK*BB*CC*MM = 409,600
    float* S   = Gt + (size_t)NKK*BB*CC*MM;           // BB*NKK*MM*CC = 409,600
    float* U   = S  + (size_t)BB*NKK*MM*CC;           // BB*NN*MM*CC  = 2,621,440
    float* FlT = U  + (size_t)BB*NN*MM*CC;            // NN*MM   =  5,120
    float* FkT = FlT + NN*MM;                         // NN*NKK  = 10,240
    float* BkT = FkT + NN*NKK;                        // NKK*NN  = 10,240
    float* BlT = BkT + NKK*NN;                        // MM*NN   =  5,120
    float* CwT = BlT + MM*NN;                         // NLAY*CC*CC = 12,288
    // total = 37,038,080 floats = 148.2 MB of workspace

    k_basis<<<1, 256, 0, stream>>>(FlT, FkT, BkT, BlT, CwT, conv_w);
    k_fc0<<<BB*NN, 256, 0, stream>>>(x, fc0_w, fc0_b, hA);

    for (int lay = 0; lay < NLAY; ++lay) {
        const float* w1 = sp_w1 + (size_t)lay*CC*CC*MM*MM;
        const float* w2 = sp_w2 + (size_t)lay*CC*CC*MM*MM;
        k_fwd<<<BB*CC*2, 256, 0, stream>>>(hA, FkT, FlT, Gt);
        k_spec<<<NKK, 256, BB*CC*MM*sizeof(float), stream>>>(Gt, w1, w2, S);
        k_inv1<<<BB*NN, 256, 0, stream>>>(S, BkT, U);
        if (lay != NLAY-1) {
            k_combine<<<BB*NN*4, 256, 0, stream>>>(
                hA, U, BlT, CwT + lay*CC*CC, conv_b + lay*CC);
        } else {
            k_combine_fc<<<BB*NN, 256, 0, stream>>>(
                hA, U, BlT, CwT + lay*CC*CC, conv_b + lay*CC,
                fc1_w, fc1_b, fc2_w, fc2_b, (float*)d_out);
        }
    }
}